// Round 7
// baseline (708.547 us; speedup 1.0000x reference)
//
#include <hip/hip_runtime.h>
#include <hip/hip_bf16.h>
#include <hip/hip_fp16.h>

typedef __attribute__((ext_vector_type(8))) _Float16 h8;
typedef __attribute__((ext_vector_type(4))) float f32x4;
typedef unsigned short u16;
typedef unsigned int u32;

#define GLOAD16(g, l)                                                          \
  __builtin_amdgcn_global_load_lds((const __attribute__((address_space(1))) u32*)(g), \
                                   (__attribute__((address_space(3))) u32*)(l), 16, 0, 0)

// ---------------- kernel 1: closed-form Cayley -> p,q vectors ----------------
__global__ __launch_bounds__(512) void prep_kernel(const float* __restrict__ r,
                                                   const float* __restrict__ d,
                                                   float* __restrict__ pq) {
  int t = threadIdx.x;
  float rv = r[t], dv = d[t];
  float s1 = rv, s2 = rv * rv;
#pragma unroll
  for (int off = 32; off; off >>= 1) {
    s1 += __shfl_down(s1, off);
    s2 += __shfl_down(s2, off);
  }
  __shared__ float a1[8], a2[8];
  if ((t & 63) == 0) { a1[t >> 6] = s1; a2[t >> 6] = s2; }
  __syncthreads();
  float S1 = 0.f, S2 = 0.f;
#pragma unroll
  for (int w = 0; w < 8; ++w) { S1 += a1[w]; S2 += a2[w]; }
  float delta = 1.f - S1 * S1 + 512.f * S2;
  float c = 2.f / delta;
  pq[t]       = c * dv * ((1.f + S1) * rv - S2);
  pq[512 + t] = -c * dv * (512.f * rv + 1.f - S1);
}

// ---------------- kernel 2: lifted via per-diagonal prefix sums (VALIDATED r5) ----
// Emits fp16 hi/lo. Storage (per 128x64 tile): elem = ((i>>7)*16 + (j>>6))*8192
//                                        + (i&127)*64 + ((j&63) ^ ((i&7)<<3))
__global__ __launch_bounds__(256) void build_lifted_diag(const float* __restrict__ rg,
                                                         const float* __restrict__ dg,
                                                         const float* __restrict__ pq,
                                                         u16* __restrict__ Lhi,
                                                         u16* __restrict__ Llo) {
  __shared__ float r_s[512], d_s[512];
  __shared__ float W[6][512];
  const int t = threadIdx.x;
  const int delta = (int)blockIdx.x - 1023;
#pragma unroll
  for (int u = 0; u < 2; ++u) {
    int a = t + (u << 8);
    r_s[a] = rg[a]; d_s[a] = dg[a]; W[0][a] = pq[a];
  }
  __syncthreads();
#pragma unroll
  for (int u = 0; u < 2; ++u) {
    int a = t + (u << 8);
    float qa = pq[512 + a];
    W[1][a] = d_s[a];
    int ap = a + delta, am = a - delta;
    int bp = 511 + delta - a, bm = 511 - delta - a;
    W[2][a] = ((unsigned)ap < 512u) ? qa * r_s[ap] : 0.f;
    W[3][a] = ((unsigned)am < 512u) ? qa * r_s[am] : 0.f;
    W[4][a] = ((unsigned)bp < 512u) ? qa * r_s[bp] : 0.f;
    W[5][a] = ((unsigned)bm < 512u) ? qa * r_s[bm] : 0.f;
  }
  __syncthreads();
  float* Wf = &W[0][0];
  for (int s = 4; s <= 256; s <<= 1) {
    float tmp[12];
#pragma unroll
    for (int u = 0; u < 12; ++u) {
      int idx = t + (u << 8);
      tmp[u] = ((idx & 511) >= s) ? Wf[idx - s] : 0.f;
    }
    __syncthreads();
#pragma unroll
    for (int u = 0; u < 12; ++u) Wf[t + (u << 8)] += tmp[u];
    __syncthreads();
  }
  const float* Pp = W[0]; const float* Pd = W[1];
  const float* CP = W[2]; const float* CM = W[3];
  const float* DP = W[4]; const float* DM = W[5];
  const int imin = max(0, -delta), imax = min(1023, 1023 - delta);
  for (int i = imin + t; i <= imax; i += 256) {
    const int j = i + delta;
    const int olo = max(0, max(i, j) - 511);
    const int ohi = min(min(i, j), 512);
    float val = 0.f;
    {
      int oc = olo + ((0 - olo) & 3);
      if (oc <= ohi) {
        int ohc = ohi - ((ohi - oc) & 3);
        int alo = i - ohc, ahi = i - oc;
        val += Pp[ahi] + CP[ahi];
        if (alo >= 4) val -= Pp[alo - 4] + CP[alo - 4];
        if (delta == 0) { val += Pd[ahi]; if (alo >= 4) val -= Pd[alo - 4]; }
      }
    }
    {
      int oc = olo + ((1 - olo) & 3);
      if (oc <= ohi) {
        int ohc = ohi - ((ohi - oc) & 3);
        int alo = j - ohc, ahi = j - oc;
        val += Pp[ahi] + DP[ahi];
        if (alo >= 4) val -= Pp[alo - 4] + DP[alo - 4];
      }
    }
    {
      int oc = olo + ((2 - olo) & 3);
      if (oc <= ohi) {
        int ohc = ohi - ((ohi - oc) & 3);
        int alo = 511 - i + oc, ahi = 511 - i + ohc;
        val += Pp[ahi] + CM[ahi];
        if (alo >= 4) val -= Pp[alo - 4] + CM[alo - 4];
        if (delta == 0) { val += Pd[ahi]; if (alo >= 4) val -= Pd[alo - 4]; }
      }
    }
    {
      int oc = olo + ((3 - olo) & 3);
      if (oc <= ohi) {
        int ohc = ohi - ((ohi - oc) & 3);
        int alo = 511 - j + oc, ahi = 511 - j + ohc;
        val += Pp[ahi] + DM[ahi];
        if (alo >= 4) val -= Pp[alo - 4] + DM[alo - 4];
      }
    }
    if (delta & 1) {
      int os = (i + j - 511) >> 1;
      if (os >= olo && os <= ohi) {
        int c = os & 3;
        if (c == 1) val += d_s[j - os];
        else if (c == 3) val += d_s[i - os];
      }
    }
    __half h = __float2half(val);
    float hf = __half2float(h);
    __half l = __float2half(val - hf);
    size_t idx = ((size_t)((i >> 7) * 16 + (j >> 6)) << 13) +
                 (size_t)((i & 127) << 6) + (size_t)((j & 63) ^ ((i & 7) << 3));
    Lhi[idx] = __half_as_ushort(h);
    Llo[idx] = __half_as_ushort(l);
  }
}

// ---------------- kernel 2b: x fp32 -> fp16, pre-swizzled staging layout ----------
// Chunk = 16384 rows. Tile (mloc 0..63, kt 0..15) = 256x64 fp16 = 32KB, linear;
// within tile: byte = r*128 + ((2*col) ^ ((r&7)<<4)).  Thread: one 16B dest block.
__global__ __launch_bounds__(256) void xcvt_kernel(const float* __restrict__ x,
                                                   u16* __restrict__ xh) {
  const int tid = blockIdx.x * 256 + threadIdx.x;   // 0 .. 2M-1
  const int tile = tid >> 11;                       // (tid*16)>>15
  const int inner = (tid << 4) & 32767;
  const int r = inner >> 7;
  const int coff = ((inner & 127) ^ ((r & 7) << 4)) >> 1;  // fp16 col offset, mult of 8
  const int mloc = tile >> 4, kt = tile & 15;
  const float* src = x + (size_t)(mloc * 256 + r) * 1024 + kt * 64 + coff;
  float4 v0 = *reinterpret_cast<const float4*>(src);
  float4 v1 = *reinterpret_cast<const float4*>(src + 4);
  union { __half2 h[4]; uint4 u; } pk;
  pk.h[0] = __floats2half2_rn(v0.x, v0.y);
  pk.h[1] = __floats2half2_rn(v0.z, v0.w);
  pk.h[2] = __floats2half2_rn(v1.x, v1.y);
  pk.h[3] = __floats2half2_rn(v1.z, v1.w);
  *reinterpret_cast<uint4*>(xh + ((size_t)tid << 3)) = pk.u;
}

// ---------------- kernel 3: pipelined fp16 2-product GEMM -------------------------
// BM=256 BN=128 BK=64, 512 thr = 8 waves (2m x 4n), per-wave out 128x32.
// 2-deep K-tile dbuf, counted vmcnt(8) (T4), setprio MFMA clusters (T5),
// one-sub-ahead ds_read overlap (T3-lite). LDS 128 KB. Race-free:
// {compute -> barrier -> STAGE(t+2 into consumed buf) -> vmcnt(8) -> barrier}.
__global__ __launch_bounds__(512, 2) void gemm2_kernel(const u16* __restrict__ Axh,
                                                       const u16* __restrict__ Lh,
                                                       const u16* __restrict__ Ll,
                                                       float* __restrict__ out) {
  __shared__ u16 Abuf[2][16384];   // 64 KB
  __shared__ u16 Hbuf[2][8192];    // 32 KB
  __shared__ u16 Lbuf[2][8192];    // 32 KB
  const int tid = threadIdx.x;
  const int nb = blockIdx.x & 7;          // n-pane pinned per XCD (validated r5)
  const int mloc = blockIdx.x >> 3;       // 0..63 within chunk
  const int lane = tid & 63;
  const int wave = tid >> 6;
  const int wm = wave >> 2, wn = wave & 3;
  const int lr = lane & 15, lg = lane >> 4;
  const int sel = (lr & 7) << 3;
  const int co0 = (lg << 3) ^ sel;        // ks0 col offset (u16)
  const int co1 = (32 + (lg << 3)) ^ sel; // ks1

  int aOff[8], bOff[2];
#pragma unroll
  for (int f = 0; f < 8; ++f) aOff[f] = ((wm << 7) + (f << 4) + lr) << 6;
#pragma unroll
  for (int f = 0; f < 2; ++f) bOff[f] = ((wn << 5) + (f << 4) + lr) << 6;

  const u16* gA = Axh + ((size_t)mloc << 18) + (tid << 3);  // mloc*16*16384
  const u16* gH = Lh + ((size_t)nb << 17) + (tid << 3);     // nb*16*8192
  const u16* gL = Ll + ((size_t)nb << 17) + (tid << 3);

#define STAGE(c, kt_) do {                                                     \
    const u16* sa = gA + ((kt_) << 14);                                        \
    const u16* sh = gH + ((kt_) << 13);                                        \
    const u16* sl = gL + ((kt_) << 13);                                        \
    GLOAD16(sa,          &Abuf[c][tid << 3]);                                  \
    GLOAD16(sa + 4096,   &Abuf[c][(tid << 3) + 4096]);                         \
    GLOAD16(sa + 8192,   &Abuf[c][(tid << 3) + 8192]);                         \
    GLOAD16(sa + 12288,  &Abuf[c][(tid << 3) + 12288]);                        \
    GLOAD16(sh,          &Hbuf[c][tid << 3]);                                  \
    GLOAD16(sh + 4096,   &Hbuf[c][(tid << 3) + 4096]);                         \
    GLOAD16(sl,          &Lbuf[c][tid << 3]);                                  \
    GLOAD16(sl + 4096,   &Lbuf[c][(tid << 3) + 4096]);                         \
  } while (0)

  f32x4 acc[8][2] = {};

  // prologue: tiles 0,1 in flight; wait tile0 (leave tile1's 8 outstanding)
  STAGE(0, 0);
  STAGE(1, 1);
  asm volatile("s_waitcnt vmcnt(8)" ::: "memory");
  __builtin_amdgcn_s_barrier();
  __builtin_amdgcn_sched_barrier(0);

  for (int t = 0; t < 16; ++t) {
    const int c = t & 1;
    const u16* Ab = Abuf[c];
    const u16* Hb = Hbuf[c];
    const u16* Lb = Lbuf[c];
    h8 aA[4], aB[4], bh0[2], bl0[2], bh1[2], bl1[2];
    // sub(0,0) reads + sub(0,1) read-ahead
#pragma unroll
    for (int f = 0; f < 4; ++f) aA[f] = *reinterpret_cast<const h8*>(&Ab[aOff[f] + co0]);
#pragma unroll
    for (int f = 0; f < 2; ++f) {
      bh0[f] = *reinterpret_cast<const h8*>(&Hb[bOff[f] + co0]);
      bl0[f] = *reinterpret_cast<const h8*>(&Lb[bOff[f] + co0]);
    }
#pragma unroll
    for (int f = 0; f < 4; ++f) aB[f] = *reinterpret_cast<const h8*>(&Ab[aOff[4 + f] + co0]);
    __builtin_amdgcn_s_setprio(1);
#pragma unroll
    for (int f = 0; f < 4; ++f) {
      acc[f][0] = __builtin_amdgcn_mfma_f32_16x16x32_f16(aA[f], bh0[0], acc[f][0], 0, 0, 0);
      acc[f][0] = __builtin_amdgcn_mfma_f32_16x16x32_f16(aA[f], bl0[0], acc[f][0], 0, 0, 0);
      acc[f][1] = __builtin_amdgcn_mfma_f32_16x16x32_f16(aA[f], bh0[1], acc[f][1], 0, 0, 0);
      acc[f][1] = __builtin_amdgcn_mfma_f32_16x16x32_f16(aA[f], bl0[1], acc[f][1], 0, 0, 0);
    }
    __builtin_amdgcn_s_setprio(0);
    // sub(1,0) reads (reuse aA) + B ks1
    h8 aC[4];
#pragma unroll
    for (int f = 0; f < 4; ++f) aC[f] = *reinterpret_cast<const h8*>(&Ab[aOff[f] + co1]);
#pragma unroll
    for (int f = 0; f < 2; ++f) {
      bh1[f] = *reinterpret_cast<const h8*>(&Hb[bOff[f] + co1]);
      bl1[f] = *reinterpret_cast<const h8*>(&Lb[bOff[f] + co1]);
    }
    __builtin_amdgcn_s_setprio(1);
#pragma unroll
    for (int f = 0; f < 4; ++f) {
      acc[4 + f][0] = __builtin_amdgcn_mfma_f32_16x16x32_f16(aB[f], bh0[0], acc[4 + f][0], 0, 0, 0);
      acc[4 + f][0] = __builtin_amdgcn_mfma_f32_16x16x32_f16(aB[f], bl0[0], acc[4 + f][0], 0, 0, 0);
      acc[4 + f][1] = __builtin_amdgcn_mfma_f32_16x16x32_f16(aB[f], bh0[1], acc[4 + f][1], 0, 0, 0);
      acc[4 + f][1] = __builtin_amdgcn_mfma_f32_16x16x32_f16(aB[f], bl0[1], acc[4 + f][1], 0, 0, 0);
    }
    __builtin_amdgcn_s_setprio(0);
    // sub(1,1) read-ahead
    h8 aD[4];
#pragma unroll
    for (int f = 0; f < 4; ++f) aD[f] = *reinterpret_cast<const h8*>(&Ab[aOff[4 + f] + co1]);
    __builtin_amdgcn_s_setprio(1);
#pragma unroll
    for (int f = 0; f < 4; ++f) {
      acc[f][0] = __builtin_amdgcn_mfma_f32_16x16x32_f16(aC[f], bh1[0], acc[f][0], 0, 0, 0);
      acc[f][0] = __builtin_amdgcn_mfma_f32_16x16x32_f16(aC[f], bl1[0], acc[f][0], 0, 0, 0);
      acc[f][1] = __builtin_amdgcn_mfma_f32_16x16x32_f16(aC[f], bh1[1], acc[f][1], 0, 0, 0);
      acc[f][1] = __builtin_amdgcn_mfma_f32_16x16x32_f16(aC[f], bl1[1], acc[f][1], 0, 0, 0);
    }
#pragma unroll
    for (int f = 0; f < 4; ++f) {
      acc[4 + f][0] = __builtin_amdgcn_mfma_f32_16x16x32_f16(aD[f], bh1[0], acc[4 + f][0], 0, 0, 0);
      acc[4 + f][0] = __builtin_amdgcn_mfma_f32_16x16x32_f16(aD[f], bl1[0], acc[4 + f][0], 0, 0, 0);
      acc[4 + f][1] = __builtin_amdgcn_mfma_f32_16x16x32_f16(aD[f], bh1[1], acc[4 + f][1], 0, 0, 0);
      acc[4 + f][1] = __builtin_amdgcn_mfma_f32_16x16x32_f16(aD[f], bl1[1], acc[4 + f][1], 0, 0, 0);
    }
    __builtin_amdgcn_s_setprio(0);

    if (t < 14) {
      __builtin_amdgcn_s_barrier();          // all waves done reading buf c
      __builtin_amdgcn_sched_barrier(0);
      STAGE(c, t + 2);                       // refill consumed buffer
      asm volatile("s_waitcnt vmcnt(8)" ::: "memory");  // tile t+1 landed
      __builtin_amdgcn_s_barrier();
      __builtin_amdgcn_sched_barrier(0);
    } else if (t == 14) {
      asm volatile("s_waitcnt vmcnt(0)" ::: "memory");  // drain tile 15
      __builtin_amdgcn_s_barrier();
      __builtin_amdgcn_sched_barrier(0);
    }
  }
#undef STAGE

  // epilogue: C/D layout col = lane&15, row = (lane>>4)*4 + reg
#pragma unroll
  for (int fm = 0; fm < 8; ++fm) {
    int row = (mloc << 8) + (wm << 7) + (fm << 4) + (lg << 2);
#pragma unroll
    for (int fn = 0; fn < 2; ++fn) {
      int col = (nb << 7) + (wn << 5) + (fn << 4) + lr;
      float* op = out + (size_t)row * 1024 + col;
#pragma unroll
      for (int rr = 0; rr < 4; ++rr) op[(size_t)rr * 1024] = acc[fm][fn][rr];
    }
  }
}

// ---------------- launch ----------------
extern "C" void kernel_launch(void* const* d_in, const int* in_sizes, int n_in,
                              void* d_out, int out_size, void* d_ws, size_t ws_size,
                              hipStream_t stream) {
  (void)in_sizes; (void)n_in; (void)out_size; (void)ws_size;
  const float* x  = (const float*)d_in[0];
  const float* r  = (const float*)d_in[1];
  const float* dg = (const float*)d_in[2];
  float* out = (float*)d_out;
  float* pq = (float*)d_ws;                           // 4 KB
  u16* Lhi = (u16*)((char*)d_ws + 4096);              // 2 MB fp16 hi
  u16* Llo = Lhi + 1024 * 1024;                       // 2 MB fp16 lo
  u16* xh  = Llo + 1024 * 1024;                       // 32 MB fp16 x-chunk (ws >= ~36.1 MB)

  prep_kernel<<<1, 512, 0, stream>>>(r, dg, pq);
  build_lifted_diag<<<2047, 256, 0, stream>>>(r, dg, pq, Lhi, Llo);
  for (int ch = 0; ch < 4; ++ch) {
    const float* xc = x + (size_t)ch * 16384 * 1024;
    float* oc = out + (size_t)ch * 16384 * 1024;
    xcvt_kernel<<<8192, 256, 0, stream>>>(xc, xh);
    gemm2_kernel<<<512, 512, 0, stream>>>(xh, Lhi, Llo, oc);
  }
}